// Round 1
// baseline (574.345 us; speedup 1.0000x reference)
//
#include <hip/hip_runtime.h>
#include <cstdint>
#include <cstddef>

// ---------------------------------------------------------------------------
// GCN: 5 layers, out = Â (x W) + b per layer, SiLU on layers 0-3.
// Â = D^-1/2 (A + I) D^-1/2 built from edge_index with self-loops.
// Strategy: aggregate-then-matmul (linearity), CSR grouped by dst (no float
// atomics), dis-prescale fused into matmul epilogue.
// ---------------------------------------------------------------------------

static __device__ __forceinline__ float silu_f(float x) {
  return x / (1.0f + __expf(-x));
}

// Detect whether edge_index is stored as int64 (odd int32 words all zero) or
// int32. flag = 1 -> int64 layout, 0 -> int32 layout.
__global__ void k_detect(const int* __restrict__ e32, int* __restrict__ flag) {
  __shared__ int any_nonzero;
  if (threadIdx.x == 0) any_nonzero = 0;
  __syncthreads();
  int v = e32[threadIdx.x * 2 + 1];
  if (v != 0) any_nonzero = 1;
  __syncthreads();
  if (threadIdx.x == 0) *flag = (any_nonzero ? 0 : 1);
}

// Histogram of dst (in-degree, excluding self-loop).
__global__ void k_count(const int* __restrict__ e32, const int* __restrict__ flag,
                        int* __restrict__ cnt, int E) {
  const int f = *flag;
  const int stride = gridDim.x * blockDim.x;
  for (int i = blockIdx.x * blockDim.x + threadIdx.x; i < E; i += stride) {
    int d = f ? e32[2 * E + 2 * i] : e32[E + i];
    atomicAdd(&cnt[d], 1);
  }
}

// dis[i] = 1/sqrt(deg) with deg = in-degree + 1 (self-loop). deg >= 1 always.
__global__ void k_deg_dis(const int* __restrict__ cnt, float* __restrict__ dis, int n) {
  int i = blockIdx.x * blockDim.x + threadIdx.x;
  if (i < n) dis[i] = 1.0f / sqrtf((float)(cnt[i] + 1));
}

// Hierarchical exclusive scan, stage 1: 1024 elems/block (4/thread).
__global__ void k_scan1(const int* __restrict__ cnt, int* __restrict__ outp,
                        int* __restrict__ bsum, int n) {
  __shared__ int wsum[4];
  const int t = threadIdx.x;
  const int base = blockIdx.x * 1024 + t * 4;
  int v0 = 0, v1 = 0, v2 = 0, v3 = 0;
  if (base + 0 < n) v0 = cnt[base + 0];
  if (base + 1 < n) v1 = cnt[base + 1];
  if (base + 2 < n) v2 = cnt[base + 2];
  if (base + 3 < n) v3 = cnt[base + 3];
  const int s = v0 + v1 + v2 + v3;
  int sc = s;
  const int lane = t & 63;
  #pragma unroll
  for (int o = 1; o < 64; o <<= 1) {
    int u = __shfl_up(sc, o);
    if (lane >= o) sc += u;
  }
  const int wid = t >> 6;
  if (lane == 63) wsum[wid] = sc;
  __syncthreads();
  int wbase = 0;
  for (int w = 0; w < wid; ++w) wbase += wsum[w];
  const int ex = wbase + sc - s;  // exclusive prefix of this thread's chunk
  if (base + 0 < n) outp[base + 0] = ex;
  if (base + 1 < n) outp[base + 1] = ex + v0;
  if (base + 2 < n) outp[base + 2] = ex + v0 + v1;
  if (base + 3 < n) outp[base + 3] = ex + v0 + v1 + v2;
  if (t == 0) bsum[blockIdx.x] = wsum[0] + wsum[1] + wsum[2] + wsum[3];
}

// Stage 2: serial exclusive scan of block sums (nblk ~ 49) + write total.
__global__ void k_scan2(int* __restrict__ bsum, int nblk, int* __restrict__ total_out) {
  if (threadIdx.x == 0 && blockIdx.x == 0) {
    int acc = 0;
    for (int i = 0; i < nblk; ++i) { int v = bsum[i]; bsum[i] = acc; acc += v; }
    *total_out = acc;
  }
}

// Stage 3: add block offsets; also init atomic cursors.
__global__ void k_scan3(int* __restrict__ rowp, int* __restrict__ cursor,
                        const int* __restrict__ bsum, int n) {
  int i = blockIdx.x * blockDim.x + threadIdx.x;
  if (i < n) {
    int v = rowp[i] + bsum[i >> 10];
    rowp[i] = v;
    cursor[i] = v;
  }
}

// Fill CSR column (src) list grouped by dst.
__global__ void k_fill(const int* __restrict__ e32, const int* __restrict__ flag,
                       int* __restrict__ cursor, int* __restrict__ col, int E) {
  const int f = *flag;
  const int stride = gridDim.x * blockDim.x;
  for (int i = blockIdx.x * blockDim.x + threadIdx.x; i < E; i += stride) {
    int s, d;
    if (f) { s = e32[2 * i]; d = e32[2 * E + 2 * i]; }
    else   { s = e32[i];     d = e32[E + i]; }
    int p = atomicAdd(&cursor[d], 1);
    col[p] = s;
  }
}

// xs3 = pos * dis[row]  (pre-scale for layer-0 aggregation)
__global__ void k_scale0(const float* __restrict__ pos, const float* __restrict__ dis,
                         float* __restrict__ xs3, int n3) {
  int i = blockIdx.x * blockDim.x + threadIdx.x;
  if (i < n3) xs3[i] = pos[i] * dis[i / 3];
}

// 3-dim aggregation: y3[i] = dis[i] * (sum_{e in in(i)} xs3[src_e] + xs3[i])
__global__ void k_agg3(const float* __restrict__ xs3, float* __restrict__ y3,
                       const int* __restrict__ rowp, const int* __restrict__ col,
                       const float* __restrict__ dis, int n) {
  int i = blockIdx.x * blockDim.x + threadIdx.x;
  if (i >= n) return;
  float a0 = xs3[i * 3 + 0], a1 = xs3[i * 3 + 1], a2 = xs3[i * 3 + 2];
  const int e0 = rowp[i], e1 = rowp[i + 1];
  for (int e = e0; e < e1; ++e) {
    int s = col[e];
    a0 += xs3[s * 3 + 0];
    a1 += xs3[s * 3 + 1];
    a2 += xs3[s * 3 + 2];
  }
  const float d = dis[i];
  y3[i * 3 + 0] = a0 * d;
  y3[i * 3 + 1] = a1 * d;
  y3[i * 3 + 2] = a2 * d;
}

// Layer 0 matmul: xs = silu(y3 @ W0 + b0) * dis.  Thread = (node, 4 cols).
__global__ void k_mm0(const float* __restrict__ y3, const float* __restrict__ W0,
                      const float* __restrict__ b0, const float* __restrict__ dis,
                      float* __restrict__ out, int n) {
  int gid = blockIdx.x * blockDim.x + threadIdx.x;
  int node = gid >> 5;
  int c = (gid & 31) << 2;
  if (node >= n) return;
  float v0 = y3[node * 3 + 0], v1 = y3[node * 3 + 1], v2 = y3[node * 3 + 2];
  float4 a  = *reinterpret_cast<const float4*>(b0 + c);
  float4 w0 = *reinterpret_cast<const float4*>(W0 + 0 * 128 + c);
  float4 w1 = *reinterpret_cast<const float4*>(W0 + 1 * 128 + c);
  float4 w2 = *reinterpret_cast<const float4*>(W0 + 2 * 128 + c);
  a.x += v0 * w0.x + v1 * w1.x + v2 * w2.x;
  a.y += v0 * w0.y + v1 * w1.y + v2 * w2.y;
  a.z += v0 * w0.z + v1 * w1.z + v2 * w2.z;
  a.w += v0 * w0.w + v1 * w1.w + v2 * w2.w;
  const float d = dis[node];
  a.x = silu_f(a.x) * d; a.y = silu_f(a.y) * d;
  a.z = silu_f(a.z) * d; a.w = silu_f(a.w) * d;
  *reinterpret_cast<float4*>(out + (size_t)node * 128 + c) = a;
}

// 128-dim aggregation: wave per node, lane holds 2 floats (float2).
// y[i] = dis[i] * (sum_{e in in(i)} xs[src_e] + xs[i])
__global__ void k_agg128(const float* __restrict__ xs, float* __restrict__ y,
                         const int* __restrict__ rowp, const int* __restrict__ col,
                         const float* __restrict__ dis, int n) {
  const int lane = threadIdx.x & 63;
  const int node = blockIdx.x * 4 + (threadIdx.x >> 6);
  if (node >= n) return;
  const int c0 = lane * 2;
  const int e0 = rowp[node], e1 = rowp[node + 1];
  float2 acc = *reinterpret_cast<const float2*>(xs + (size_t)node * 128 + c0);  // self
  int e = e0;
  for (; e + 2 <= e1; e += 2) {
    int s0 = col[e], s1 = col[e + 1];
    float2 v0 = *reinterpret_cast<const float2*>(xs + (size_t)s0 * 128 + c0);
    float2 v1 = *reinterpret_cast<const float2*>(xs + (size_t)s1 * 128 + c0);
    acc.x += v0.x + v1.x;
    acc.y += v0.y + v1.y;
  }
  if (e < e1) {
    int s0 = col[e];
    float2 v0 = *reinterpret_cast<const float2*>(xs + (size_t)s0 * 128 + c0);
    acc.x += v0.x;
    acc.y += v0.y;
  }
  const float d = dis[node];
  acc.x *= d; acc.y *= d;
  *reinterpret_cast<float2*>(y + (size_t)node * 128 + c0) = acc;
}

// Middle matmul: out = silu(x @ W + b) * dis   (fuse=1)  [N x 128]x[128 x 128]
// Tile 32 rows x 128 cols, 256 threads, 4x4 register blocking, W staged in LDS.
__global__ __launch_bounds__(256) void k_mm_mid(
    const float* __restrict__ x, const float* __restrict__ W,
    const float* __restrict__ bias, const float* __restrict__ dis,
    float* __restrict__ out, int n, int fuse) {
  __shared__ float xs[32][128];
  __shared__ float ws[32][128];
  const int t = threadIdx.x;
  const int row0 = blockIdx.x * 32;

  // stage x tile (32 x 128), zero-padded past n
  {
    int i = t;
    #pragma unroll
    for (int it = 0; it < 4; ++it, i += 256) {
      int r = i >> 5;
      int c4 = (i & 31) << 2;
      float4 v = make_float4(0.f, 0.f, 0.f, 0.f);
      int row = row0 + r;
      if (row < n) v = *reinterpret_cast<const float4*>(x + (size_t)row * 128 + c4);
      *reinterpret_cast<float4*>(&xs[r][c4]) = v;
    }
  }

  const int tc = (t & 31) << 2;  // 4 cols
  const int tr = (t >> 5) << 2;  // 4 rows
  float4 acc[4];
  #pragma unroll
  for (int r = 0; r < 4; ++r) acc[r] = make_float4(0.f, 0.f, 0.f, 0.f);

  for (int kc = 0; kc < 128; kc += 32) {
    __syncthreads();
    // stage W[kc..kc+32)[0..128)
    {
      int i = t;
      #pragma unroll
      for (int it = 0; it < 4; ++it, i += 256) {
        int r = i >> 5;
        int c4 = (i & 31) << 2;
        *reinterpret_cast<float4*>(&ws[r][c4]) =
            *reinterpret_cast<const float4*>(W + (size_t)(kc + r) * 128 + c4);
      }
    }
    __syncthreads();
    #pragma unroll
    for (int k = 0; k < 32; ++k) {
      float4 w4 = *reinterpret_cast<const float4*>(&ws[k][tc]);
      float x0 = xs[tr + 0][kc + k];
      float x1 = xs[tr + 1][kc + k];
      float x2 = xs[tr + 2][kc + k];
      float x3 = xs[tr + 3][kc + k];
      acc[0].x += x0 * w4.x; acc[0].y += x0 * w4.y; acc[0].z += x0 * w4.z; acc[0].w += x0 * w4.w;
      acc[1].x += x1 * w4.x; acc[1].y += x1 * w4.y; acc[1].z += x1 * w4.z; acc[1].w += x1 * w4.w;
      acc[2].x += x2 * w4.x; acc[2].y += x2 * w4.y; acc[2].z += x2 * w4.z; acc[2].w += x2 * w4.w;
      acc[3].x += x3 * w4.x; acc[3].y += x3 * w4.y; acc[3].z += x3 * w4.z; acc[3].w += x3 * w4.w;
    }
  }

  float4 bb = *reinterpret_cast<const float4*>(bias + tc);
  #pragma unroll
  for (int r = 0; r < 4; ++r) {
    int row = row0 + tr + r;
    if (row < n) {
      float4 a = acc[r];
      a.x += bb.x; a.y += bb.y; a.z += bb.z; a.w += bb.w;
      if (fuse) {
        float d = dis[row];
        a.x = silu_f(a.x) * d; a.y = silu_f(a.y) * d;
        a.z = silu_f(a.z) * d; a.w = silu_f(a.w) * d;
      }
      *reinterpret_cast<float4*>(out + (size_t)row * 128 + tc) = a;
    }
  }
}

// Last layer: out[node][0..3) = x[node] @ W4 + b4 (128 -> 3). Wave per node.
__global__ void k_mm_last(const float* __restrict__ x, const float* __restrict__ W4,
                          const float* __restrict__ b4, float* __restrict__ out, int n) {
  const int lane = threadIdx.x & 63;
  const int node = blockIdx.x * 4 + (threadIdx.x >> 6);
  if (node >= n) return;
  float a = x[(size_t)node * 128 + lane];
  float b = x[(size_t)node * 128 + 64 + lane];
  float wa0 = W4[lane * 3 + 0], wa1 = W4[lane * 3 + 1], wa2 = W4[lane * 3 + 2];
  float wb0 = W4[(lane + 64) * 3 + 0], wb1 = W4[(lane + 64) * 3 + 1], wb2 = W4[(lane + 64) * 3 + 2];
  float s0 = a * wa0 + b * wb0;
  float s1 = a * wa1 + b * wb1;
  float s2 = a * wa2 + b * wb2;
  #pragma unroll
  for (int o = 32; o >= 1; o >>= 1) {
    s0 += __shfl_down(s0, o);
    s1 += __shfl_down(s1, o);
    s2 += __shfl_down(s2, o);
  }
  if (lane == 0) {
    out[node * 3 + 0] = s0 + b4[0];
    out[node * 3 + 1] = s1 + b4[1];
    out[node * 3 + 2] = s2 + b4[2];
  }
}

extern "C" void kernel_launch(void* const* d_in, const int* in_sizes, int n_in,
                              void* d_out, int out_size, void* d_ws, size_t ws_size,
                              hipStream_t stream) {
  const float* pos = (const float*)d_in[0];
  const int* e32 = (const int*)d_in[1];
  const float* W[5] = {(const float*)d_in[2], (const float*)d_in[4], (const float*)d_in[6],
                       (const float*)d_in[8], (const float*)d_in[10]};
  const float* B[5] = {(const float*)d_in[3], (const float*)d_in[5], (const float*)d_in[7],
                       (const float*)d_in[9], (const float*)d_in[11]};
  float* out = (float*)d_out;

  const int N = in_sizes[0] / 3;
  const int E = in_sizes[1] / 2;

  char* base = (char*)d_ws;
  size_t off = 0;
  auto alloc = [&](size_t bytes) -> void* {
    void* p = base + off;
    off += (bytes + 255) & ~(size_t)255;
    return p;
  };
  float* dis  = (float*)alloc((size_t)N * 4);
  int* cnt    = (int*)alloc((size_t)N * 4);
  int* rowp   = (int*)alloc((size_t)(N + 1) * 4);
  int* cursor = (int*)alloc((size_t)N * 4);
  int* bsum   = (int*)alloc(64 * 4);
  int* flag   = (int*)alloc(256);
  int* col    = (int*)alloc((size_t)E * 4);
  float* xs3  = (float*)alloc((size_t)N * 3 * 4);
  float* y3   = (float*)alloc((size_t)N * 3 * 4);
  float* bufA = (float*)alloc((size_t)N * 128 * 4);
  float* bufB = (float*)alloc((size_t)N * 128 * 4);

  const int nblk = (N + 1023) / 1024;  // 49 for N=50000 (bsum holds up to 64)

  // --- CSR build (deterministic per call; no state carried across calls) ---
  hipMemsetAsync(cnt, 0, (size_t)N * 4, stream);
  k_detect<<<1, 256, 0, stream>>>(e32, flag);
  k_count<<<1024, 256, 0, stream>>>(e32, flag, cnt, E);
  k_deg_dis<<<(N + 255) / 256, 256, 0, stream>>>(cnt, dis, N);
  k_scan1<<<nblk, 256, 0, stream>>>(cnt, rowp, bsum, N);
  k_scan2<<<1, 64, 0, stream>>>(bsum, nblk, rowp + N);
  k_scan3<<<(N + 255) / 256, 256, 0, stream>>>(rowp, cursor, bsum, N);
  k_fill<<<1024, 256, 0, stream>>>(e32, flag, cursor, col, E);

  // --- layer 0: aggregate pos (3-dim) then 3->128 matmul + SiLU + dis ---
  k_scale0<<<(N * 3 + 255) / 256, 256, 0, stream>>>(pos, dis, xs3, N * 3);
  k_agg3<<<(N + 255) / 256, 256, 0, stream>>>(xs3, y3, rowp, col, dis, N);
  k_mm0<<<(N * 32 + 255) / 256, 256, 0, stream>>>(y3, W[0], B[0], dis, bufA, N);

  // --- layers 1..3: aggregate (128) then 128x128 matmul + SiLU + dis ---
  for (int l = 1; l <= 3; ++l) {
    k_agg128<<<(N + 3) / 4, 256, 0, stream>>>(bufA, bufB, rowp, col, dis, N);
    k_mm_mid<<<(N + 31) / 32, 256, 0, stream>>>(bufB, W[l], B[l], dis, bufA, N, 1);
  }

  // --- layer 4: aggregate (128) then 128->3 matmul (no SiLU, no dis) ---
  k_agg128<<<(N + 3) / 4, 256, 0, stream>>>(bufA, bufB, rowp, col, dis, N);
  k_mm_last<<<(N + 3) / 4, 256, 0, stream>>>(bufB, W[4], B[4], out, N);

  (void)n_in; (void)out_size; (void)ws_size;
}

// Round 2
// 500.216 us; speedup vs baseline: 1.1482x; 1.1482x over previous
//
#include <hip/hip_runtime.h>
#include <cstdint>
#include <cstddef>

// ---------------------------------------------------------------------------
// GCN: 5 layers, out = Â (x W) + b per layer, SiLU on layers 0-3.
// Â = D^-1/2 (A + I) D^-1/2 built from edge_index with self-loops.
// Strategy: aggregate in the LOWEST-dim space (linearity): layer 0 aggregates
// the 3-dim input, layer 4 matmuls 128->3 FIRST then aggregates 3-dim.
// CSR grouped by dst (no float atomics); dis-prescale fused into epilogues.
// ---------------------------------------------------------------------------

static __device__ __forceinline__ float silu_f(float x) {
  return x / (1.0f + __expf(-x));
}

// Detect whether edge_index is stored as int64 (odd int32 words all zero) or
// int32. flag = 1 -> int64 layout, 0 -> int32 layout.
__global__ void k_detect(const int* __restrict__ e32, int* __restrict__ flag) {
  __shared__ int any_nonzero;
  if (threadIdx.x == 0) any_nonzero = 0;
  __syncthreads();
  int v = e32[threadIdx.x * 2 + 1];
  if (v != 0) any_nonzero = 1;
  __syncthreads();
  if (threadIdx.x == 0) *flag = (any_nonzero ? 0 : 1);
}

// Histogram of dst (in-degree, excluding self-loop).
__global__ void k_count(const int* __restrict__ e32, const int* __restrict__ flag,
                        int* __restrict__ cnt, int E) {
  const int f = *flag;
  const int stride = gridDim.x * blockDim.x;
  for (int i = blockIdx.x * blockDim.x + threadIdx.x; i < E; i += stride) {
    int d = f ? e32[2 * E + 2 * i] : e32[E + i];
    atomicAdd(&cnt[d], 1);
  }
}

// Hierarchical exclusive scan, stage 1: 1024 elems/block (4/thread).
// Also emits dis[i] = 1/sqrt(deg_i + 1) (self-loop included; always >= 1).
__global__ void k_scan1(const int* __restrict__ cnt, int* __restrict__ outp,
                        int* __restrict__ bsum, float* __restrict__ dis, int n) {
  __shared__ int wsum[4];
  const int t = threadIdx.x;
  const int base = blockIdx.x * 1024 + t * 4;
  int v0 = 0, v1 = 0, v2 = 0, v3 = 0;
  if (base + 0 < n) v0 = cnt[base + 0];
  if (base + 1 < n) v1 = cnt[base + 1];
  if (base + 2 < n) v2 = cnt[base + 2];
  if (base + 3 < n) v3 = cnt[base + 3];
  if (base + 0 < n) dis[base + 0] = 1.0f / sqrtf((float)(v0 + 1));
  if (base + 1 < n) dis[base + 1] = 1.0f / sqrtf((float)(v1 + 1));
  if (base + 2 < n) dis[base + 2] = 1.0f / sqrtf((float)(v2 + 1));
  if (base + 3 < n) dis[base + 3] = 1.0f / sqrtf((float)(v3 + 1));
  const int s = v0 + v1 + v2 + v3;
  int sc = s;
  const int lane = t & 63;
  #pragma unroll
  for (int o = 1; o < 64; o <<= 1) {
    int u = __shfl_up(sc, o);
    if (lane >= o) sc += u;
  }
  const int wid = t >> 6;
  if (lane == 63) wsum[wid] = sc;
  __syncthreads();
  int wbase = 0;
  for (int w = 0; w < wid; ++w) wbase += wsum[w];
  const int ex = wbase + sc - s;  // exclusive prefix of this thread's chunk
  if (base + 0 < n) outp[base + 0] = ex;
  if (base + 1 < n) outp[base + 1] = ex + v0;
  if (base + 2 < n) outp[base + 2] = ex + v0 + v1;
  if (base + 3 < n) outp[base + 3] = ex + v0 + v1 + v2;
  if (t == 0) bsum[blockIdx.x] = wsum[0] + wsum[1] + wsum[2] + wsum[3];
}

// Stage 2: serial exclusive scan of block sums (nblk ~ 49) + write total.
__global__ void k_scan2(int* __restrict__ bsum, int nblk, int* __restrict__ total_out) {
  if (threadIdx.x == 0 && blockIdx.x == 0) {
    int acc = 0;
    for (int i = 0; i < nblk; ++i) { int v = bsum[i]; bsum[i] = acc; acc += v; }
    *total_out = acc;
  }
}

// Stage 3: add block offsets; init atomic cursors; also xs3 = pos * dis[row]
// (pre-scale for layer-0 aggregation).
__global__ void k_scan3(int* __restrict__ rowp, int* __restrict__ cursor,
                        const int* __restrict__ bsum, const float* __restrict__ pos,
                        const float* __restrict__ dis, float* __restrict__ xs3, int n) {
  int i = blockIdx.x * blockDim.x + threadIdx.x;
  if (i < n) {
    int v = rowp[i] + bsum[i >> 10];
    rowp[i] = v;
    cursor[i] = v;
    float d = dis[i];
    xs3[3 * i + 0] = pos[3 * i + 0] * d;
    xs3[3 * i + 1] = pos[3 * i + 1] * d;
    xs3[3 * i + 2] = pos[3 * i + 2] * d;
  }
}

// Fill CSR column (src) list grouped by dst.
__global__ void k_fill(const int* __restrict__ e32, const int* __restrict__ flag,
                       int* __restrict__ cursor, int* __restrict__ col, int E) {
  const int f = *flag;
  const int stride = gridDim.x * blockDim.x;
  for (int i = blockIdx.x * blockDim.x + threadIdx.x; i < E; i += stride) {
    int s, d;
    if (f) { s = e32[2 * i]; d = e32[2 * E + 2 * i]; }
    else   { s = e32[i];     d = e32[E + i]; }
    int p = atomicAdd(&cursor[d], 1);
    col[p] = s;
  }
}

// 3-dim aggregation: out3[i] = bias + dis[i] * (sum_{e in in(i)} in3[src_e] + in3[i])
// in3 must already be dis-prescaled. bias nullable.
__global__ void k_agg3(const float* __restrict__ in3, float* __restrict__ out3,
                       const int* __restrict__ rowp, const int* __restrict__ col,
                       const float* __restrict__ dis, const float* __restrict__ bias,
                       int n) {
  int i = blockIdx.x * blockDim.x + threadIdx.x;
  if (i >= n) return;
  float a0 = in3[i * 3 + 0], a1 = in3[i * 3 + 1], a2 = in3[i * 3 + 2];
  const int e0 = rowp[i], e1 = rowp[i + 1];
  for (int e = e0; e < e1; ++e) {
    int s = col[e];
    a0 += in3[s * 3 + 0];
    a1 += in3[s * 3 + 1];
    a2 += in3[s * 3 + 2];
  }
  const float d = dis[i];
  a0 *= d; a1 *= d; a2 *= d;
  if (bias) { a0 += bias[0]; a1 += bias[1]; a2 += bias[2]; }
  out3[i * 3 + 0] = a0;
  out3[i * 3 + 1] = a1;
  out3[i * 3 + 2] = a2;
}

// Layer 0 matmul: xs = silu(y3 @ W0 + b0) * dis.  Thread = (node, 4 cols).
__global__ void k_mm0(const float* __restrict__ y3, const float* __restrict__ W0,
                      const float* __restrict__ b0, const float* __restrict__ dis,
                      float* __restrict__ out, int n) {
  int gid = blockIdx.x * blockDim.x + threadIdx.x;
  int node = gid >> 5;
  int c = (gid & 31) << 2;
  if (node >= n) return;
  float v0 = y3[node * 3 + 0], v1 = y3[node * 3 + 1], v2 = y3[node * 3 + 2];
  float4 a  = *reinterpret_cast<const float4*>(b0 + c);
  float4 w0 = *reinterpret_cast<const float4*>(W0 + 0 * 128 + c);
  float4 w1 = *reinterpret_cast<const float4*>(W0 + 1 * 128 + c);
  float4 w2 = *reinterpret_cast<const float4*>(W0 + 2 * 128 + c);
  a.x += v0 * w0.x + v1 * w1.x + v2 * w2.x;
  a.y += v0 * w0.y + v1 * w1.y + v2 * w2.y;
  a.z += v0 * w0.z + v1 * w1.z + v2 * w2.z;
  a.w += v0 * w0.w + v1 * w1.w + v2 * w2.w;
  const float d = dis[node];
  a.x = silu_f(a.x) * d; a.y = silu_f(a.y) * d;
  a.z = silu_f(a.z) * d; a.w = silu_f(a.w) * d;
  *reinterpret_cast<float4*>(out + (size_t)node * 128 + c) = a;
}

// 128-dim aggregation: wave per node, lane holds 2 floats (float2).
// y[i] = dis[i] * (sum_{e in in(i)} xs[src_e] + xs[i]); 4-deep load pipelining.
__global__ void k_agg128(const float* __restrict__ xs, float* __restrict__ y,
                         const int* __restrict__ rowp, const int* __restrict__ col,
                         const float* __restrict__ dis, int n) {
  const int lane = threadIdx.x & 63;
  const int node = blockIdx.x * 4 + (threadIdx.x >> 6);
  if (node >= n) return;
  const float* __restrict__ xc = xs + lane * 2;
  const int e0 = rowp[node], e1 = rowp[node + 1];
  float2 acc0 = *reinterpret_cast<const float2*>(xc + (size_t)node * 128);  // self
  float2 acc1 = make_float2(0.f, 0.f);
  int e = e0;
  for (; e + 4 <= e1; e += 4) {
    int s0 = col[e], s1 = col[e + 1], s2 = col[e + 2], s3 = col[e + 3];
    float2 v0 = *reinterpret_cast<const float2*>(xc + (size_t)s0 * 128);
    float2 v1 = *reinterpret_cast<const float2*>(xc + (size_t)s1 * 128);
    float2 v2 = *reinterpret_cast<const float2*>(xc + (size_t)s2 * 128);
    float2 v3 = *reinterpret_cast<const float2*>(xc + (size_t)s3 * 128);
    acc0.x += v0.x + v1.x; acc0.y += v0.y + v1.y;
    acc1.x += v2.x + v3.x; acc1.y += v2.y + v3.y;
  }
  for (; e < e1; ++e) {
    int s = col[e];
    float2 v = *reinterpret_cast<const float2*>(xc + (size_t)s * 128);
    acc0.x += v.x; acc0.y += v.y;
  }
  const float d = dis[node];
  float2 r;
  r.x = (acc0.x + acc1.x) * d;
  r.y = (acc0.y + acc1.y) * d;
  *reinterpret_cast<float2*>(y + (size_t)node * 128 + lane * 2) = r;
}

// Middle matmul: out = silu(x @ W + b) * dis   [N x 128]x[128 x 128]
// Tile 32 rows x 128 cols, 256 threads, 4x4 register blocking, W staged in LDS.
__global__ __launch_bounds__(256) void k_mm_mid(
    const float* __restrict__ x, const float* __restrict__ W,
    const float* __restrict__ bias, const float* __restrict__ dis,
    float* __restrict__ out, int n) {
  __shared__ float xs[32][128];
  __shared__ float ws[32][128];
  const int t = threadIdx.x;
  const int row0 = blockIdx.x * 32;

  // stage x tile (32 x 128), zero-padded past n
  {
    int i = t;
    #pragma unroll
    for (int it = 0; it < 4; ++it, i += 256) {
      int r = i >> 5;
      int c4 = (i & 31) << 2;
      float4 v = make_float4(0.f, 0.f, 0.f, 0.f);
      int row = row0 + r;
      if (row < n) v = *reinterpret_cast<const float4*>(x + (size_t)row * 128 + c4);
      *reinterpret_cast<float4*>(&xs[r][c4]) = v;
    }
  }

  const int tc = (t & 31) << 2;  // 4 cols
  const int tr = (t >> 5) << 2;  // 4 rows
  float4 acc[4];
  #pragma unroll
  for (int r = 0; r < 4; ++r) acc[r] = make_float4(0.f, 0.f, 0.f, 0.f);

  for (int kc = 0; kc < 128; kc += 32) {
    __syncthreads();
    // stage W[kc..kc+32)[0..128)
    {
      int i = t;
      #pragma unroll
      for (int it = 0; it < 4; ++it, i += 256) {
        int r = i >> 5;
        int c4 = (i & 31) << 2;
        *reinterpret_cast<float4*>(&ws[r][c4]) =
            *reinterpret_cast<const float4*>(W + (size_t)(kc + r) * 128 + c4);
      }
    }
    __syncthreads();
    #pragma unroll
    for (int k = 0; k < 32; ++k) {
      float4 w4 = *reinterpret_cast<const float4*>(&ws[k][tc]);
      float x0 = xs[tr + 0][kc + k];
      float x1 = xs[tr + 1][kc + k];
      float x2 = xs[tr + 2][kc + k];
      float x3 = xs[tr + 3][kc + k];
      acc[0].x += x0 * w4.x; acc[0].y += x0 * w4.y; acc[0].z += x0 * w4.z; acc[0].w += x0 * w4.w;
      acc[1].x += x1 * w4.x; acc[1].y += x1 * w4.y; acc[1].z += x1 * w4.z; acc[1].w += x1 * w4.w;
      acc[2].x += x2 * w4.x; acc[2].y += x2 * w4.y; acc[2].z += x2 * w4.z; acc[2].w += x2 * w4.w;
      acc[3].x += x3 * w4.x; acc[3].y += x3 * w4.y; acc[3].z += x3 * w4.z; acc[3].w += x3 * w4.w;
    }
  }

  float4 bb = *reinterpret_cast<const float4*>(bias + tc);
  #pragma unroll
  for (int r = 0; r < 4; ++r) {
    int row = row0 + tr + r;
    if (row < n) {
      float4 a = acc[r];
      a.x += bb.x; a.y += bb.y; a.z += bb.z; a.w += bb.w;
      float d = dis[row];
      a.x = silu_f(a.x) * d; a.y = silu_f(a.y) * d;
      a.z = silu_f(a.z) * d; a.w = silu_f(a.w) * d;
      *reinterpret_cast<float4*>(out + (size_t)row * 128 + tc) = a;
    }
  }
}

// Layer-4 pre-matmul: h3[node] = x[node] @ W4 (128 -> 3), NO bias.
// x is already dis-prescaled, so h3 = dis * (x_raw @ W4) — the exact message
// term for the 3-dim aggregation. Wave per node.
__global__ void k_mm_pre3(const float* __restrict__ x, const float* __restrict__ W4,
                          float* __restrict__ h3, int n) {
  const int lane = threadIdx.x & 63;
  const int node = blockIdx.x * 4 + (threadIdx.x >> 6);
  if (node >= n) return;
  float a = x[(size_t)node * 128 + lane];
  float b = x[(size_t)node * 128 + 64 + lane];
  float wa0 = W4[lane * 3 + 0], wa1 = W4[lane * 3 + 1], wa2 = W4[lane * 3 + 2];
  float wb0 = W4[(lane + 64) * 3 + 0], wb1 = W4[(lane + 64) * 3 + 1], wb2 = W4[(lane + 64) * 3 + 2];
  float s0 = a * wa0 + b * wb0;
  float s1 = a * wa1 + b * wb1;
  float s2 = a * wa2 + b * wb2;
  #pragma unroll
  for (int o = 32; o >= 1; o >>= 1) {
    s0 += __shfl_down(s0, o);
    s1 += __shfl_down(s1, o);
    s2 += __shfl_down(s2, o);
  }
  if (lane == 0) {
    h3[node * 3 + 0] = s0;
    h3[node * 3 + 1] = s1;
    h3[node * 3 + 2] = s2;
  }
}

extern "C" void kernel_launch(void* const* d_in, const int* in_sizes, int n_in,
                              void* d_out, int out_size, void* d_ws, size_t ws_size,
                              hipStream_t stream) {
  const float* pos = (const float*)d_in[0];
  const int* e32 = (const int*)d_in[1];
  const float* W[5] = {(const float*)d_in[2], (const float*)d_in[4], (const float*)d_in[6],
                       (const float*)d_in[8], (const float*)d_in[10]};
  const float* B[5] = {(const float*)d_in[3], (const float*)d_in[5], (const float*)d_in[7],
                       (const float*)d_in[9], (const float*)d_in[11]};
  float* out = (float*)d_out;

  const int N = in_sizes[0] / 3;
  const int E = in_sizes[1] / 2;

  char* base = (char*)d_ws;
  size_t off = 0;
  auto alloc = [&](size_t bytes) -> void* {
    void* p = base + off;
    off += (bytes + 255) & ~(size_t)255;
    return p;
  };
  float* dis  = (float*)alloc((size_t)N * 4);
  int* cnt    = (int*)alloc((size_t)N * 4);
  int* rowp   = (int*)alloc((size_t)(N + 1) * 4);
  int* cursor = (int*)alloc((size_t)N * 4);
  int* bsum   = (int*)alloc(64 * 4);
  int* flag   = (int*)alloc(256);
  int* col    = (int*)alloc((size_t)E * 4);
  float* xs3  = (float*)alloc((size_t)N * 3 * 4);
  float* y3   = (float*)alloc((size_t)N * 3 * 4);
  float* bufA = (float*)alloc((size_t)N * 128 * 4);
  float* bufB = (float*)alloc((size_t)N * 128 * 4);

  const int nblk = (N + 1023) / 1024;  // 49 for N=50000 (bsum holds up to 64)

  // --- CSR build (deterministic per call; no state carried across calls) ---
  hipMemsetAsync(cnt, 0, (size_t)N * 4, stream);
  k_detect<<<1, 256, 0, stream>>>(e32, flag);
  k_count<<<1024, 256, 0, stream>>>(e32, flag, cnt, E);
  k_scan1<<<nblk, 256, 0, stream>>>(cnt, rowp, bsum, dis, N);
  k_scan2<<<1, 64, 0, stream>>>(bsum, nblk, rowp + N);
  k_scan3<<<(N + 255) / 256, 256, 0, stream>>>(rowp, cursor, bsum, pos, dis, xs3, N);
  k_fill<<<1024, 256, 0, stream>>>(e32, flag, cursor, col, E);

  // --- layer 0: aggregate pos (3-dim) then 3->128 matmul + SiLU + dis ---
  k_agg3<<<(N + 255) / 256, 256, 0, stream>>>(xs3, y3, rowp, col, dis, nullptr, N);
  k_mm0<<<(N * 32 + 255) / 256, 256, 0, stream>>>(y3, W[0], B[0], dis, bufA, N);

  // --- layers 1..3: aggregate (128) then 128x128 matmul + SiLU + dis ---
  for (int l = 1; l <= 3; ++l) {
    k_agg128<<<(N + 3) / 4, 256, 0, stream>>>(bufA, bufB, rowp, col, dis, N);
    k_mm_mid<<<(N + 31) / 32, 256, 0, stream>>>(bufB, W[l], B[l], dis, bufA, N);
  }

  // --- layer 4: matmul FIRST (128->3, message term), then 3-dim aggregate ---
  k_mm_pre3<<<(N + 3) / 4, 256, 0, stream>>>(bufA, W[4], y3, N);
  k_agg3<<<(N + 255) / 256, 256, 0, stream>>>(y3, out, rowp, col, dis, B[4], N);

  (void)n_in; (void)out_size; (void)ws_size;
}